// Round 1
// 1473.922 us; speedup vs baseline: 1.2953x; 1.2953x over previous
//
#include <hip/hip_runtime.h>

// LinearRNNwithSoftExp on MI355X (gfx950)  T=1024, B=512, D=128, H=256.
// Round 3: fold the bf16 hi+lo precision split into unused MFMA A-rows.
// Rows 0..3 of the A fragment carry [h0_hi, h1_hi, h0_lo, h1_lo]; one MFMA
// pass produces hi and lo contributions in separate C rows (all quad 0),
// combined with 2 fp32 adds. Recurrent MFMAs/wave/step: 64 -> 32; af
// ds_read_b128: 16 -> 8. Also prefetch data one extra step ahead so the
// staged load's vmcnt never sits on the pre-barrier critical path.
// h LDS layout [ping][k/8][row(4)][k%8]: reads and writes are <=2-way.

#define BB 512
#define DD 128
#define HH 256

typedef __attribute__((ext_vector_type(8))) short bf16x8;
typedef __attribute__((ext_vector_type(4))) float f32x4;

static __device__ __forceinline__ short f2bf(float f) {
    unsigned u = __float_as_uint(f);
    u += 0x7FFFu + ((u >> 16) & 1u);   // round-to-nearest-even
    return (short)(u >> 16);
}
static __device__ __forceinline__ float bf2f(short s) {
    return __uint_as_float(((unsigned)(unsigned short)s) << 16);
}
static __device__ __forceinline__ bf16x8 pack8(const float4 a, const float4 b) {
    bf16x8 v;
    v[0] = f2bf(a.x); v[1] = f2bf(a.y); v[2] = f2bf(a.z); v[3] = f2bf(a.w);
    v[4] = f2bf(b.x); v[5] = f2bf(b.y); v[6] = f2bf(b.z); v[7] = f2bf(b.w);
    return v;
}

__global__ __launch_bounds__(512, 2)
void rnn_fused(const float* __restrict__ data, const float* __restrict__ ih_w,
               const float* __restrict__ ih_b, const float* __restrict__ hh_w,
               const float* __restrict__ hh_b, const int* __restrict__ lengths,
               float* __restrict__ out)
{
    const int g    = blockIdx.x;
    const int tid  = threadIdx.x;
    const int w    = tid >> 6;     // wave 0..7
    const int lane = tid & 63;
    const int col  = lane & 15;    // MFMA n-col / A-row index
    const int quad = lane >> 4;    // k-quad

    // h state, bf16 hi+lo folded into A-rows:
    // [ping][kf = k/8][row: 0=h0hi 1=h1hi 2=h0lo 3=h1lo][slot = k%8]
    // read banks: (quad*16 + row*4) % 32 -> 2-way max (free).
    // write banks: 16 lanes over 8 banks -> 2-way (free).
    __shared__ short hbuf[2][32][4][8];
    // data staging, bf16: [ping][row(2)][k(128)]
    __shared__ short dbuf[2][2][DD];

    // ---- persistent weight fragments in registers ----
    // whh[s*2+j][i]: s=0 alpha rows 32w+16j, s=1 hbar rows 256+32w+16j
    bf16x8 whh[4][8];
    #pragma unroll
    for (int s = 0; s < 2; ++s)
        #pragma unroll
        for (int j = 0; j < 2; ++j) {
            const int wrow = s*HH + 32*w + 16*j + col;
            const float* src = hh_w + wrow * HH;
            #pragma unroll
            for (int i = 0; i < 8; ++i) {
                const float4 a = *(const float4*)(src + i*32 + quad*8);
                const float4 b = *(const float4*)(src + i*32 + quad*8 + 4);
                whh[s*2 + j][i] = pack8(a, b);
            }
        }
    bf16x8 wih[2][4];
    #pragma unroll
    for (int j = 0; j < 2; ++j) {
        const int wrow = 32*w + 16*j + col;
        const float* src = ih_w + wrow * DD;
        #pragma unroll
        for (int i = 0; i < 4; ++i) {
            const float4 a = *(const float4*)(src + i*32 + quad*8);
            const float4 b = *(const float4*)(src + i*32 + quad*8 + 4);
            wih[j][i] = pack8(a, b);
        }
    }

    float bA[2], bH[2], bX[2];
    #pragma unroll
    for (int j = 0; j < 2; ++j) {
        bA[j] = hh_b[      32*w + 16*j + col];
        bH[j] = hh_b[HH  + 32*w + 16*j + col];
        bX[j] = ih_b[      32*w + 16*j + col];
    }

    const int L0 = lengths[2*g];
    const int L1 = lengths[2*g + 1];
    const int Lmax = (L0 > L1) ? L0 : L1;

    // ---- prologue: zero h, stage data[0], prefetch data[1] into a reg ----
    for (int idx = tid; idx < 32*4*8; idx += 512)
        ((short*)hbuf[0])[idx] = 0;
    if (tid < 256)
        ((short*)dbuf[0])[tid] = f2bf(data[(size_t)(2*g) * DD + tid]);
    float vstage = 0.f;
    if (tid < 256 && 1 < Lmax)
        vstage = data[((size_t)1 * BB + 2*g) * DD + tid];
    __syncthreads();

    float  nh[2][2] = {{0.f,0.f},{0.f,0.f}};
    bf16x8 af[4] = {};   // h A-frags (non-act lanes stay 0 forever)
    bf16x8 dh[4] = {};   // data A-frags

    const bool act = (col < 4);          // A-rows 0..3 are real (hi0,hi1,lo0,lo1)

    for (int t = 0; t < Lmax; ++t) {
        const int p = t & 1;

        // ---- publish data[t+1] (loaded >=1 full step ago; vmcnt long clear)
        if (tid < 256 && t + 1 < Lmax)
            ((short*)dbuf[1 - p])[tid] = f2bf(vstage);
        // ---- issue load of data[t+2]; lands during this step + next
        float vnew = 0.f;
        if (tid < 256 && t + 2 < Lmax)
            vnew = data[((size_t)(t+2) * BB + 2*g) * DD + tid];

        // ---- recurrent matmul: single pass, hi in C-rows 0..1, lo in 2..3
        f32x4 racc[4];
        #pragma unroll
        for (int j = 0; j < 2; ++j) {
            f32x4 va = {bA[j], bA[j], 0.f, 0.f}; racc[j]     = va;
            f32x4 vh = {bH[j], bH[j], 0.f, 0.f}; racc[2 + j] = vh;
        }
        #pragma unroll
        for (int half = 0; half < 2; ++half) {      // k-frags 0-3, 4-7
            if (act) {
                #pragma unroll
                for (int i = 0; i < 4; ++i)
                    af[i] = *(const bf16x8*)
                        &hbuf[p][(half*4 + i)*4 + quad][col][0];
            }
            #pragma unroll
            for (int i = 0; i < 4; ++i)
                #pragma unroll
                for (int tt = 0; tt < 4; ++tt)
                    racc[tt] = __builtin_amdgcn_mfma_f32_16x16x32_bf16(
                        af[i], whh[tt][half*4 + i], racc[tt], 0, 0, 0);
        }

        // ---- x-projection: data[t] @ ih_w^T + ih_b ----
        if (act && col < 2) {
            #pragma unroll
            for (int i = 0; i < 4; ++i)
                dh[i] = *(const bf16x8*)&dbuf[p][col][i*32 + quad*8];
        }
        f32x4 xacc[2];
        #pragma unroll
        for (int j = 0; j < 2; ++j) {
            f32x4 v = {bX[j], bX[j], bX[j], bX[j]}; xacc[j] = v;
        }
        #pragma unroll
        for (int i = 0; i < 4; ++i)
            #pragma unroll
            for (int j = 0; j < 2; ++j)
                xacc[j] = __builtin_amdgcn_mfma_f32_16x16x32_bf16(
                    dh[i], wih[j][i], xacc[j], 0, 0, 0);

        // ---- epilogue: combine hi+lo, sigmoid, soft-exp gate, tanh, mask ----
        // C/D layout: col = lane&15, row = quad*4 + reg; rows 0..3 in quad 0.
        #pragma unroll
        for (int j = 0; j < 2; ++j) {
            #pragma unroll
            for (int r = 0; r < 2; ++r) {
                const float a   = racc[j][r]     + racc[j][2 + r];
                const float hv  = racc[2 + j][r] + racc[2 + j][2 + r];
                const float e   = __builtin_amdgcn_exp2f(a * -1.4426950408889634f);
                const float inv = 1.0f + e;                    // exactly 1/alpha
                const float al  = __builtin_amdgcn_rcpf(inv);  // alpha
                const float pp  = __builtin_amdgcn_exp2f(al * hv);
                const float gg  = (pp - 1.0f) * inv + al;
                const float u   = xacc[j][r] + gg;
                const float t2  = __builtin_amdgcn_exp2f(u * 2.8853900817779268f);
                const float th  = 1.0f - 2.0f * __builtin_amdgcn_rcpf(1.0f + t2);
                const int   Lr  = r ? L1 : L0;
                const float v   = (t < Lr) ? th : nh[j][r];
                nh[j][r] = v;
                if (quad == 0) {
                    const int   c  = 32*w + 16*j + col;   // h element index
                    const short hi = f2bf(v);
                    const short lo = f2bf(v - bf2f(hi));
                    hbuf[1 - p][c >> 3][r    ][c & 7] = hi;
                    hbuf[1 - p][c >> 3][2 + r][c & 7] = lo;
                }
            }
        }

        vstage = vnew;
        __syncthreads();
    }

    // ---- final hidden state -> out [1, B, H] fp32 ----
    if (quad == 0) {
        #pragma unroll
        for (int j = 0; j < 2; ++j)
            #pragma unroll
            for (int r = 0; r < 2; ++r)
                out[(size_t)(2*g + r) * HH + 32*w + 16*j + col] = nh[j][r];
    }
}

extern "C" void kernel_launch(void* const* d_in, const int* in_sizes, int n_in,
                              void* d_out, int out_size, void* d_ws, size_t ws_size,
                              hipStream_t stream) {
    const float* data    = (const float*)d_in[0];
    const float* ih_w    = (const float*)d_in[1];
    const float* ih_b    = (const float*)d_in[2];
    const float* hh_w    = (const float*)d_in[3];
    const float* hh_b    = (const float*)d_in[4];
    const int*   lengths = (const int*)d_in[5];
    float* out = (float*)d_out;

    (void)in_sizes; (void)n_in; (void)out_size; (void)d_ws; (void)ws_size;

    rnn_fused<<<dim3(BB / 2), dim3(512), 0, stream>>>(
        data, ih_w, ih_b, hh_w, hh_b, lengths, out);
}

// Round 2
// 1363.524 us; speedup vs baseline: 1.4002x; 1.0810x over previous
//
#include <hip/hip_runtime.h>

// LinearRNNwithSoftExp on MI355X (gfx950)  T=1024, B=512, D=128, H=256.
// Round 4: latency-bound (MfmaUtil 29 / VALU 24 / occ 16) -> double TLP.
// 1024 threads = 16 waves per block (1 block/CU, 4 waves/SIMD). Wave w owns
// 16 output cols: alpha rows [16w,16w+16), hbar rows [256+16w,...), x rows
// [16w,16w+16). Per-wave: 16 recurrent + 4 xproj MFMAs (half of round 3);
// per-SIMD issue identical, but 4 waves hide ds_read/MFMA-chain/epilogue
// latency. VGPR diet for the 128-cap: biases folded into epilogue (zero acc
// init), one shared 4-frag block for h A-frags and data A-frags (data loads
// masked col<2; A-rows 2-3 garbage lands in ignored C rows).
// hi/lo bf16 h-state fold in A-rows 0..3 kept from round 3 (absmax 6.8e-3).

#define BB 512
#define DD 128
#define HH 256

typedef __attribute__((ext_vector_type(8))) short bf16x8;
typedef __attribute__((ext_vector_type(4))) float f32x4;

static __device__ __forceinline__ short f2bf(float f) {
    unsigned u = __float_as_uint(f);
    u += 0x7FFFu + ((u >> 16) & 1u);   // round-to-nearest-even
    return (short)(u >> 16);
}
static __device__ __forceinline__ float bf2f(short s) {
    return __uint_as_float(((unsigned)(unsigned short)s) << 16);
}
static __device__ __forceinline__ bf16x8 pack8(const float4 a, const float4 b) {
    bf16x8 v;
    v[0] = f2bf(a.x); v[1] = f2bf(a.y); v[2] = f2bf(a.z); v[3] = f2bf(a.w);
    v[4] = f2bf(b.x); v[5] = f2bf(b.y); v[6] = f2bf(b.z); v[7] = f2bf(b.w);
    return v;
}

__global__ __launch_bounds__(1024, 4)
void rnn_fused(const float* __restrict__ data, const float* __restrict__ ih_w,
               const float* __restrict__ ih_b, const float* __restrict__ hh_w,
               const float* __restrict__ hh_b, const int* __restrict__ lengths,
               float* __restrict__ out)
{
    const int g    = blockIdx.x;
    const int tid  = threadIdx.x;
    const int w    = tid >> 6;     // wave 0..15
    const int lane = tid & 63;
    const int col  = lane & 15;    // MFMA n-col / A-row index
    const int quad = lane >> 4;    // k-quad

    // h state, bf16 hi+lo folded into A-rows:
    // [ping][kf = k/8][row: 0=h0hi 1=h1hi 2=h0lo 3=h1lo][slot = k%8]
    __shared__ short hbuf[2][32][4][8];
    // data staging, bf16: [ping][row(2)][k(128)]
    __shared__ short dbuf[2][2][DD];

    // ---- persistent weight fragments in registers ----
    // whh[s][i]: s=0 alpha row 16w+col, s=1 hbar row 256+16w+col
    bf16x8 whh[2][8];
    #pragma unroll
    for (int s = 0; s < 2; ++s) {
        const int wrow = s*HH + 16*w + col;
        const float* src = hh_w + wrow * HH;
        #pragma unroll
        for (int i = 0; i < 8; ++i) {
            const float4 a = *(const float4*)(src + i*32 + quad*8);
            const float4 b = *(const float4*)(src + i*32 + quad*8 + 4);
            whh[s][i] = pack8(a, b);
        }
    }
    bf16x8 wih[4];
    {
        const int wrow = 16*w + col;
        const float* src = ih_w + wrow * DD;
        #pragma unroll
        for (int i = 0; i < 4; ++i) {
            const float4 a = *(const float4*)(src + i*32 + quad*8);
            const float4 b = *(const float4*)(src + i*32 + quad*8 + 4);
            wih[i] = pack8(a, b);
        }
    }

    const float bA = hh_b[      16*w + col];
    const float bH = hh_b[HH  + 16*w + col];
    const float bX = ih_b[      16*w + col];

    const int L0 = lengths[2*g];
    const int L1 = lengths[2*g + 1];
    const int Lmax = (L0 > L1) ? L0 : L1;

    // ---- prologue: zero h ping 0, stage data[0], prefetch data[1] ----
    for (int idx = tid; idx < 32*4*8; idx += 1024)
        ((short*)hbuf[0])[idx] = 0;
    if (tid < 256)
        ((short*)dbuf[0])[tid] = f2bf(data[(size_t)(2*g) * DD + tid]);
    float vstage = 0.f;
    if (tid < 256 && 1 < Lmax)
        vstage = data[((size_t)1 * BB + 2*g) * DD + tid];
    __syncthreads();

    float  nh[2] = {0.f, 0.f};
    bf16x8 frag[4] = {};   // shared A-frags: h (col<4) then data (col<2)

    const bool acth = (col < 4);   // A-rows 0..3 real for recurrent matmul
    const bool actd = (col < 2);   // A-rows 0..1 real for x-projection

    for (int t = 0; t < Lmax; ++t) {
        const int p = t & 1;

        // ---- publish data[t+1] (loaded a full step ago), issue data[t+2]
        if (tid < 256 && t + 1 < Lmax)
            ((short*)dbuf[1 - p])[tid] = f2bf(vstage);
        float vnew = 0.f;
        if (tid < 256 && t + 2 < Lmax)
            vnew = data[((size_t)(t+2) * BB + 2*g) * DD + tid];

        // ---- recurrent matmul: hi in C-rows 0..1, lo in 2..3, zero C-init
        f32x4 racc[2] = {{0.f,0.f,0.f,0.f},{0.f,0.f,0.f,0.f}};
        #pragma unroll
        for (int half = 0; half < 2; ++half) {      // k-frags 0-3, 4-7
            if (acth) {
                #pragma unroll
                for (int i = 0; i < 4; ++i)
                    frag[i] = *(const bf16x8*)
                        &hbuf[p][(half*4 + i)*4 + quad][col][0];
            }
            #pragma unroll
            for (int i = 0; i < 4; ++i)
                #pragma unroll
                for (int s = 0; s < 2; ++s)
                    racc[s] = __builtin_amdgcn_mfma_f32_16x16x32_bf16(
                        frag[i], whh[s][half*4 + i], racc[s], 0, 0, 0);
        }

        // ---- x-projection: data[t] @ ih_w^T (bias folded below) ----
        if (actd) {
            #pragma unroll
            for (int i = 0; i < 4; ++i)
                frag[i] = *(const bf16x8*)&dbuf[p][col][i*32 + quad*8];
        }
        f32x4 xacc = {0.f, 0.f, 0.f, 0.f};
        #pragma unroll
        for (int i = 0; i < 4; ++i)
            xacc = __builtin_amdgcn_mfma_f32_16x16x32_bf16(
                frag[i], wih[i], xacc, 0, 0, 0);

        // ---- epilogue: combine hi+lo+bias, sigmoid, soft-exp, tanh, mask
        // C/D layout: col = lane&15, row = quad*4 + reg; rows 0..3 in quad 0.
        #pragma unroll
        for (int r = 0; r < 2; ++r) {
            const float a   = racc[0][r] + racc[0][2 + r] + bA;
            const float hv  = racc[1][r] + racc[1][2 + r] + bH;
            const float e   = __builtin_amdgcn_exp2f(a * -1.4426950408889634f);
            const float inv = 1.0f + e;                    // exactly 1/alpha
            const float al  = __builtin_amdgcn_rcpf(inv);  // alpha
            const float pp  = __builtin_amdgcn_exp2f(al * hv);
            const float gg  = (pp - 1.0f) * inv + al;
            const float u   = xacc[r] + bX + gg;
            const float t2  = __builtin_amdgcn_exp2f(u * 2.8853900817779268f);
            const float th  = 1.0f - 2.0f * __builtin_amdgcn_rcpf(1.0f + t2);
            const int   Lr  = r ? L1 : L0;
            const float v   = (t < Lr) ? th : nh[r];
            nh[r] = v;
            if (quad == 0) {
                const int   c  = 16*w + col;   // h element index 0..255
                const short hi = f2bf(v);
                const short lo = f2bf(v - bf2f(hi));
                hbuf[1 - p][c >> 3][r    ][c & 7] = hi;
                hbuf[1 - p][c >> 3][2 + r][c & 7] = lo;
            }
        }

        vstage = vnew;
        __syncthreads();
    }

    // ---- final hidden state -> out [1, B, H] fp32 ----
    if (quad == 0) {
        #pragma unroll
        for (int r = 0; r < 2; ++r)
            out[(size_t)(2*g + r) * HH + 16*w + col] = nh[r];
    }
}

extern "C" void kernel_launch(void* const* d_in, const int* in_sizes, int n_in,
                              void* d_out, int out_size, void* d_ws, size_t ws_size,
                              hipStream_t stream) {
    const float* data    = (const float*)d_in[0];
    const float* ih_w    = (const float*)d_in[1];
    const float* ih_b    = (const float*)d_in[2];
    const float* hh_w    = (const float*)d_in[3];
    const float* hh_b    = (const float*)d_in[4];
    const int*   lengths = (const int*)d_in[5];
    float* out = (float*)d_out;

    (void)in_sizes; (void)n_in; (void)out_size; (void)d_ws; (void)ws_size;

    rnn_fused<<<dim3(BB / 2), dim3(1024), 0, stream>>>(
        data, ih_w, ih_b, hh_w, hh_b, lengths, out);
}